// Round 2
// baseline (192.552 us; speedup 1.0000x reference)
//
#include <hip/hip_runtime.h>

#define NE 32   // electrons
#define NA 8    // atoms
#define DF 4    // dist features
#define KD 8    // kernel dim
#define ED 16   // embedding dim
#define BATCH 4096

typedef float f32x2 __attribute__((ext_vector_type(2)));

__device__ __forceinline__ f32x2 splat2(float s) { f32x2 r; r.x = s; r.y = s; return r; }
__device__ __forceinline__ f32x2 fma2(f32x2 a, f32x2 b, f32x2 c) {
    return __builtin_elementwise_fma(a, b, c);
}

// w-subnet on two distance-feature rows at once (packed fp32).
// Produces wv[k] = y[k] + B2h[k] where true weight w[k] = ln2 * wv[k]
// (the ln2 and the ssp's -ln2 shift are folded into B2h / a final z-scale).
__device__ __forceinline__ void wnet2(const float4 e0, const float4 e1,
                                      const f32x2* __restrict__ B1s,
                                      const float* __restrict__ pW1,   // (DF,6)
                                      const float* __restrict__ pW2,   // (6,KD)
                                      const f32x2* __restrict__ B2h,
                                      f32x2* __restrict__ wv)
{
    const float LOG2E = 1.4426950408889634f;
    f32x2 ex, ey, ez, ew;
    ex.x = e0.x; ex.y = e1.x;
    ey.x = e0.y; ey.y = e1.y;
    ez.x = e0.z; ez.y = e1.z;
    ew.x = e0.w; ew.y = e1.w;
    ex = ex * splat2(LOG2E);
    ey = ey * splat2(LOG2E);
    ez = ez * splat2(LOG2E);
    ew = ew * splat2(LOG2E);

    f32x2 r[6];
    #pragma unroll
    for (int a = 0; a < 6; ++a) {
        f32x2 u = B1s[a];                       // wb1[a]*log2e, splatted
        u = fma2(ex, splat2(pW1[0 * 6 + a]), u);
        u = fma2(ey, splat2(pW1[1 * 6 + a]), u);
        u = fma2(ez, splat2(pW1[2 * 6 + a]), u);
        u = fma2(ew, splat2(pW1[3 * 6 + a]), u);
        // r = log2(1 + 2^u)   (ssp(v) = ln2*r - ln2, folded out)
        f32x2 t;
        t.x = __builtin_amdgcn_exp2f(u.x);
        t.y = __builtin_amdgcn_exp2f(u.y);
        t = t + splat2(1.0f);
        r[a].x = __builtin_amdgcn_logf(t.x);    // v_log_f32 = log2
        r[a].y = __builtin_amdgcn_logf(t.y);
    }

    #pragma unroll
    for (int k = 0; k < KD; ++k) {
        f32x2 acc = B2h[k];
        #pragma unroll
        for (int a = 0; a < 6; ++a)
            acc = fma2(r[a], splat2(pW2[a * KD + k]), acc);
        wv[k] = acc;
    }
}

__global__ __launch_bounds__(256) void omni_kernel(
    const float* __restrict__ dists_nuc,   // (B, NE, NA, DF)
    const float* __restrict__ dists_elec,  // (B, NE, NE, DF)
    const float* __restrict__ X,           // (1, ED)
    const float* __restrict__ Y,           // (NA, KD)
    const float* __restrict__ w1,          // (2, DF, 6)
    const float* __restrict__ wb1,         // (2, 6)
    const float* __restrict__ w2,          // (2, 6, KD)
    const float* __restrict__ wb2,         // (2, KD)
    const float* __restrict__ hs_w,        // (2, ED, KD)
    const float* __restrict__ hs_b,        // (2, KD)
    const float* __restrict__ ha_w,        // (2, ED, KD)
    const float* __restrict__ ha_b,        // (2, KD)
    const float* __restrict__ g_w,         // (2, KD, ED)
    const float* __restrict__ g_b,         // (2, ED)
    const float* __restrict__ orb_w,       // (ED,)
    float* __restrict__ out)               // (B,)
{
    const int tid  = threadIdx.x;
    const int wid  = tid >> 6;        // wave in block 0..3
    const int el   = wid >> 1;        // batch-elem slot in block (0,1)
    const int q    = wid & 1;         // this wave owns j-spin-half q
    const int lane = tid & 63;
    const int i    = lane & 31;       // electron index
    const int p    = lane >> 5;       // sub-half
    const int qq   = 2 * q + p;       // j quarter: this lane covers j in [8qq, 8qq+8)
    const int b    = blockIdx.x * 2 + el;
    const int si   = i >> 4;          // spin of electron i
    const int t32  = (q == si) ? 0 : 32;  // msg table base (hs rows 0-31, ha rows 32-63)

    __shared__ float msg[2][65][KD];        // [elem][row][k]; row 64 = zeros (mask trick)
    __shared__ float zbuf[2][2][NE][KD];    // [elem][wave q][i][k]

    if (q == 0 && lane < KD) msg[el][64][lane] = 0.0f;

    float x[ED];
    #pragma unroll
    for (int c = 0; c < ED; ++c) x[c] = X[c];

    const float* de = dists_elec + ((size_t)b * NE + i) * NE * DF;
    const float* dn = dists_nuc  + ((size_t)b * NE + i) * NA * DF;

    const float LOG2E = 1.4426950408889634f;
    const float LN2   = 0.6931471805599453f;

    #pragma unroll 1
    for (int n = 0; n < 2; ++n) {
        const float* pW1 = w1  + n * DF * 6;
        const float* pB1 = wb1 + n * 6;
        const float* pW2 = w2  + n * 6 * KD;
        const float* pB2 = wb2 + n * KD;

        f32x2 B1s[6];
        #pragma unroll
        for (int a = 0; a < 6; ++a) B1s[a] = splat2(pB1[a] * LOG2E);

        // B2h[k] = wb2[k]/ln2 - sum_a w2[a][k]   (so true w[k] = ln2*(y[k]+B2h[k]))
        f32x2 B2h[KD];
        #pragma unroll
        for (int k = 0; k < KD; ++k) {
            float sw = pW2[0 * KD + k];
            #pragma unroll
            for (int a = 1; a < 6; ++a) sw += pW2[a * KD + k];
            B2h[k] = splat2(fmaf(pB2[k], LOG2E, -sw));
        }

        // ---- phase 1: wave q computes its msg table (q=0 -> hs, q=1 -> ha) ----
        {
            const float* mw = (q == 0 ? hs_w : ha_w) + n * ED * KD;
            const float* mb = (q == 0 ? hs_b : ha_b) + n * KD;
            float mi[KD];
            #pragma unroll
            for (int k = 0; k < KD; ++k) mi[k] = mb[k];
            #pragma unroll
            for (int c = 0; c < ED; ++c) {
                const float xc = x[c];
                #pragma unroll
                for (int k = 0; k < KD; ++k) mi[k] = fmaf(xc, mw[c * KD + k], mi[k]);
            }
            __syncthreads();   // prior-iteration readers done
            if (p == 0) {
                #pragma unroll
                for (int k = 0; k < KD; ++k) msg[el][q * 32 + i][k] = mi[k];
            }
            __syncthreads();
        }

        float zl[KD], zh[KD];
        #pragma unroll
        for (int k = 0; k < KD; ++k) { zl[k] = 0.0f; zh[k] = 0.0f; }

        // ---- electron messages: 8 j's per lane, 2 per packed step ----
        #pragma unroll
        for (int s = 0; s < 4; ++s) {
            const int j0 = 8 * qq + 2 * s;
            const int j1 = j0 + 1;
            const float4 e0 = *(const float4*)(de + j0 * DF);
            const float4 e1 = *(const float4*)(de + j1 * DF);
            f32x2 wv[KD];
            wnet2(e0, e1, B1s, pW1, pW2, B2h, wv);
            const float* m0 = &msg[el][(j0 == i) ? 64 : (t32 + j0)][0];
            const float* m1 = &msg[el][(j1 == i) ? 64 : (t32 + j1)][0];
            #pragma unroll
            for (int k = 0; k < KD; ++k) {
                zl[k] = fmaf(wv[k].x, m0[k], zl[k]);
                zh[k] = fmaf(wv[k].y, m1[k], zh[k]);
            }
        }

        // ---- nuclear messages: 2 atoms per lane, one packed step ----
        {
            const int m0i = 2 * qq;
            const int m1i = m0i + 1;
            const float4 f0 = *(const float4*)(dn + m0i * DF);
            const float4 f1 = *(const float4*)(dn + m1i * DF);
            f32x2 wv[KD];
            wnet2(f0, f1, B1s, pW1, pW2, B2h, wv);
            const float* y0 = Y + m0i * KD;
            const float* y1 = Y + m1i * KD;
            #pragma unroll
            for (int k = 0; k < KD; ++k) {
                zl[k] = fmaf(wv[k].x, y0[k], zl[k]);
                zh[k] = fmaf(wv[k].y, y1[k], zh[k]);
            }
        }

        // ---- combine: sub-halves, then the two waves of this elem ----
        float z[KD];
        #pragma unroll
        for (int k = 0; k < KD; ++k) z[k] = (zl[k] + zh[k]) * LN2;
        #pragma unroll
        for (int k = 0; k < KD; ++k) z[k] += __shfl_xor(z[k], 32, 64);

        if (p == 0) {
            #pragma unroll
            for (int k = 0; k < KD; ++k) zbuf[el][q][i][k] = z[k];
        }
        __syncthreads();
        #pragma unroll
        for (int k = 0; k < KD; ++k) z[k] += zbuf[el][1 - q][i][k];

        // ---- residual update ----
        #pragma unroll
        for (int c = 0; c < ED; ++c) {
            float acc = g_b[n * ED + c];
            #pragma unroll
            for (int k = 0; k < KD; ++k)
                acc = fmaf(z[k], g_w[n * KD * ED + k * ED + c], acc);
            x[c] += acc;
        }
    }

    // ---- orbital projection + sum over electrons ----
    float dot = 0.0f;
    #pragma unroll
    for (int c = 0; c < ED; ++c) dot = fmaf(x[c], orb_w[c], dot);
    dot *= 0.5f;   // each electron appears twice per wave (p=0,1)
    #pragma unroll
    for (int off = 32; off > 0; off >>= 1) dot += __shfl_xor(dot, off, 64);
    if (q == 0 && lane == 0) out[b] = dot;
}

extern "C" void kernel_launch(void* const* d_in, const int* in_sizes, int n_in,
                              void* d_out, int out_size, void* d_ws, size_t ws_size,
                              hipStream_t stream) {
    const float* dists_nuc  = (const float*)d_in[0];
    const float* dists_elec = (const float*)d_in[1];
    const float* X     = (const float*)d_in[2];
    const float* Y     = (const float*)d_in[3];
    const float* w1    = (const float*)d_in[4];
    const float* wb1   = (const float*)d_in[5];
    const float* w2    = (const float*)d_in[6];
    const float* wb2   = (const float*)d_in[7];
    const float* hs_w  = (const float*)d_in[8];
    const float* hs_b  = (const float*)d_in[9];
    const float* ha_w  = (const float*)d_in[10];
    const float* ha_b  = (const float*)d_in[11];
    const float* g_w   = (const float*)d_in[12];
    const float* g_b   = (const float*)d_in[13];
    const float* orb_w = (const float*)d_in[14];
    float* out = (float*)d_out;

    dim3 grid(BATCH / 2), block(256);
    omni_kernel<<<grid, block, 0, stream>>>(dists_nuc, dists_elec, X, Y,
                                            w1, wb1, w2, wb2,
                                            hs_w, hs_b, ha_w, ha_b,
                                            g_w, g_b, orb_w, out);
}

// Round 3
// 167.734 us; speedup vs baseline: 1.1480x; 1.1480x over previous
//
#include <hip/hip_runtime.h>

#define NE 32   // electrons
#define NA 8    // atoms
#define DF 4    // dist features
#define KD 8    // kernel dim
#define ED 16   // embedding dim
#define BATCH 4096

__device__ __forceinline__ float exp2_fast(float v) { return __builtin_amdgcn_exp2f(v); }
__device__ __forceinline__ float log2_fast(float v) { return __builtin_amdgcn_logf(v); }

// log-domain w-subnet: racc[k] such that true weight w[k] = ln2 * racc[k].
// u_a = (e@W1 + b1)*log2e  (e prescaled);  r_a = log2(1 + 2^u_a)
// racc[k] = sum_a r_a * W2[a][k] + B2h[k],  B2h[k] = wb2[k]*log2e - sum_a W2[a][k]
__device__ __forceinline__ void wnet1(const float4 e,
                                      const float* __restrict__ B1s,   // 6, VGPR uniform
                                      const float* __restrict__ pW1,   // (DF,6) SGPR
                                      const float* __restrict__ pW2,   // (6,KD) SGPR
                                      const float* __restrict__ B2h,   // 8, VGPR uniform
                                      float* __restrict__ racc)
{
    const float LOG2E = 1.4426950408889634f;
    const float ex = e.x * LOG2E, ey = e.y * LOG2E;
    const float ez = e.z * LOG2E, ew = e.w * LOG2E;
    float r[6];
    #pragma unroll
    for (int a = 0; a < 6; ++a) {
        float u = B1s[a];
        u = fmaf(ex, pW1[0 * 6 + a], u);
        u = fmaf(ey, pW1[1 * 6 + a], u);
        u = fmaf(ez, pW1[2 * 6 + a], u);
        u = fmaf(ew, pW1[3 * 6 + a], u);
        r[a] = log2_fast(exp2_fast(u) + 1.0f);
    }
    #pragma unroll
    for (int k = 0; k < KD; ++k) {
        float acc = B2h[k];
        #pragma unroll
        for (int a = 0; a < 6; ++a) acc = fmaf(r[a], pW2[a * KD + k], acc);
        racc[k] = acc;
    }
}

__global__ __launch_bounds__(128, 4) void omni_kernel(
    const float* __restrict__ dists_nuc,   // (B, NE, NA, DF)
    const float* __restrict__ dists_elec,  // (B, NE, NE, DF)
    const float* __restrict__ X,           // (1, ED)
    const float* __restrict__ Y,           // (NA, KD)
    const float* __restrict__ w1,          // (2, DF, 6)
    const float* __restrict__ wb1,         // (2, 6)
    const float* __restrict__ w2,          // (2, 6, KD)
    const float* __restrict__ wb2,         // (2, KD)
    const float* __restrict__ hs_w,        // (2, ED, KD)
    const float* __restrict__ hs_b,        // (2, KD)
    const float* __restrict__ ha_w,        // (2, ED, KD)
    const float* __restrict__ ha_b,        // (2, KD)
    const float* __restrict__ g_w,         // (2, KD, ED)
    const float* __restrict__ g_b,         // (2, ED)
    const float* __restrict__ orb_w,       // (ED,)
    float* __restrict__ out)               // (B,)
{
    const int tid  = threadIdx.x;
    const int h    = tid >> 6;         // wave: owns electrons of spin h
    const int lane = tid & 63;
    const int il   = lane & 15;        // local electron
    const int jh   = lane >> 4;        // j quarter 0..3 (j in [8jh, 8jh+8))
    const int ig   = 16 * h + il;      // global electron index
    const int b    = blockIdx.x;
    const int sj   = jh >> 1;          // spin of this lane's j range
    const int t32  = (sj == h) ? 0 : 32;   // msg table base: same spin -> hs(0), anti -> ha(32)

    __shared__ float msg[2][65][KD];   // [interaction][row][k]; row 64 = zeros
    __shared__ float part[2];

    if (tid < 16) msg[tid >> 3][64][tid & 7] = 0.0f;

    float x[ED];
    #pragma unroll
    for (int c = 0; c < ED; ++c) x[c] = X[c];

    const float* de = dists_elec + (((size_t)b * NE + ig) * NE + 8 * jh) * DF;
    const float* dn = dists_nuc  + (((size_t)b * NE + ig) * NA + 2 * jh) * DF;

    const float LOG2E = 1.4426950408889634f;
    const float LN2   = 0.6931471805599453f;

    #pragma unroll 1
    for (int n = 0; n < 2; ++n) {
        const float* pW1 = w1  + n * DF * 6;
        const float* pB1 = wb1 + n * 6;
        const float* pW2 = w2  + n * 6 * KD;
        const float* pB2 = wb2 + n * KD;

        float B1s[6];
        #pragma unroll
        for (int a = 0; a < 6; ++a) B1s[a] = pB1[a] * LOG2E;

        float B2h[KD];
        #pragma unroll
        for (int k = 0; k < KD; ++k) {
            float sw = pW2[k];
            #pragma unroll
            for (int a = 1; a < 6; ++a) sw += pW2[a * KD + k];
            B2h[k] = fmaf(pB2[k], LOG2E, -sw);
        }

        // ---- phase 1: every lane computes hs & ha for its own electron; 2 lanes publish ----
        {
            float ms[KD], ma[KD];
            #pragma unroll
            for (int k = 0; k < KD; ++k) { ms[k] = hs_b[n * KD + k]; ma[k] = ha_b[n * KD + k]; }
            #pragma unroll
            for (int c = 0; c < ED; ++c) {
                const float xc = x[c];
                #pragma unroll
                for (int k = 0; k < KD; ++k) {
                    ms[k] = fmaf(xc, hs_w[n * ED * KD + c * KD + k], ms[k]);
                    ma[k] = fmaf(xc, ha_w[n * ED * KD + c * KD + k], ma[k]);
                }
            }
            if (jh == 0) {
                #pragma unroll
                for (int k = 0; k < KD; ++k) msg[n][ig][k] = ms[k];
            } else if (jh == 2) {
                #pragma unroll
                for (int k = 0; k < KD; ++k) msg[n][32 + ig][k] = ma[k];
            }
            __syncthreads();
        }

        float z[KD];
        #pragma unroll
        for (int k = 0; k < KD; ++k) z[k] = 0.0f;

        // ---- electron messages: 8 j's per lane ----
        #pragma unroll
        for (int s = 0; s < 8; ++s) {
            const int j = 8 * jh + s;
            const float4 e = ((const float4*)de)[s];
            float racc[KD];
            wnet1(e, B1s, pW1, pW2, B2h, racc);
            const int row = (j == ig) ? 64 : (t32 + j);   // self -> zero row
            const float4 m0 = *(const float4*)&msg[n][row][0];
            const float4 m1 = *(const float4*)&msg[n][row][4];
            z[0] = fmaf(racc[0], m0.x, z[0]);
            z[1] = fmaf(racc[1], m0.y, z[1]);
            z[2] = fmaf(racc[2], m0.z, z[2]);
            z[3] = fmaf(racc[3], m0.w, z[3]);
            z[4] = fmaf(racc[4], m1.x, z[4]);
            z[5] = fmaf(racc[5], m1.y, z[5]);
            z[6] = fmaf(racc[6], m1.z, z[6]);
            z[7] = fmaf(racc[7], m1.w, z[7]);
        }

        // ---- nuclear messages: 2 atoms per lane ----
        #pragma unroll
        for (int t = 0; t < 2; ++t) {
            const int m = 2 * jh + t;
            const float4 e = ((const float4*)dn)[t];
            float racc[KD];
            wnet1(e, B1s, pW1, pW2, B2h, racc);
            const float4 y0 = ((const float4*)Y)[m * 2];
            const float4 y1 = ((const float4*)Y)[m * 2 + 1];
            z[0] = fmaf(racc[0], y0.x, z[0]);
            z[1] = fmaf(racc[1], y0.y, z[1]);
            z[2] = fmaf(racc[2], y0.z, z[2]);
            z[3] = fmaf(racc[3], y0.w, z[3]);
            z[4] = fmaf(racc[4], y1.x, z[4]);
            z[5] = fmaf(racc[5], y1.y, z[5]);
            z[6] = fmaf(racc[6], y1.z, z[6]);
            z[7] = fmaf(racc[7], y1.w, z[7]);
        }

        // ---- sum the 4 j-quarter partials (in-wave) and rescale ----
        #pragma unroll
        for (int k = 0; k < KD; ++k) {
            z[k] += __shfl_xor(z[k], 16, 64);
            z[k] += __shfl_xor(z[k], 32, 64);
            z[k] *= LN2;
        }

        // ---- residual update (own electron only; 4 lane copies stay coherent) ----
        #pragma unroll
        for (int c = 0; c < ED; ++c) {
            float acc = g_b[n * ED + c];
            #pragma unroll
            for (int k = 0; k < KD; ++k)
                acc = fmaf(z[k], g_w[n * KD * ED + k * ED + c], acc);
            x[c] += acc;
        }
    }

    // ---- orbital projection + sum over this wave's electrons ----
    float dot = 0.0f;
    #pragma unroll
    for (int c = 0; c < ED; ++c) dot = fmaf(x[c], orb_w[c], dot);
    dot *= 0.25f;   // each electron replicated in 4 lanes
    #pragma unroll
    for (int off = 1; off < 64; off <<= 1) dot += __shfl_xor(dot, off, 64);
    if (lane == 0) part[h] = dot;
    __syncthreads();
    if (tid == 0) out[b] = part[0] + part[1];
}

extern "C" void kernel_launch(void* const* d_in, const int* in_sizes, int n_in,
                              void* d_out, int out_size, void* d_ws, size_t ws_size,
                              hipStream_t stream) {
    const float* dists_nuc  = (const float*)d_in[0];
    const float* dists_elec = (const float*)d_in[1];
    const float* X     = (const float*)d_in[2];
    const float* Y     = (const float*)d_in[3];
    const float* w1    = (const float*)d_in[4];
    const float* wb1   = (const float*)d_in[5];
    const float* w2    = (const float*)d_in[6];
    const float* wb2   = (const float*)d_in[7];
    const float* hs_w  = (const float*)d_in[8];
    const float* hs_b  = (const float*)d_in[9];
    const float* ha_w  = (const float*)d_in[10];
    const float* ha_b  = (const float*)d_in[11];
    const float* g_w   = (const float*)d_in[12];
    const float* g_b   = (const float*)d_in[13];
    const float* orb_w = (const float*)d_in[14];
    float* out = (float*)d_out;

    dim3 grid(BATCH), block(128);
    omni_kernel<<<grid, block, 0, stream>>>(dists_nuc, dists_elec, X, Y,
                                            w1, wb1, w2, wb2,
                                            hs_w, hs_b, ha_w, ha_b,
                                            g_w, g_b, orb_w, out);
}

// Round 4
// 156.340 us; speedup vs baseline: 1.2316x; 1.0729x over previous
//
#include <hip/hip_runtime.h>

#define NE 32   // electrons
#define NA 8    // atoms
#define DF 4    // dist features
#define KD 8    // kernel dim
#define ED 16   // embedding dim
#define BATCH 4096

// d_ws layout (floats)
#define WS_W1S0 0     // w1[n=0]*log2e   (d*6+a), 24
#define WS_W1S1 24
#define WS_B1S0 48    // wb1*log2e, 6 each
#define WS_B1S1 54
#define WS_B2H0 60    // wb2*log2e - sum_a w2[a][k], 8 each
#define WS_B2H1 68
#define WS_MS0  76    // n=0 same-spin msg vector, 8
#define WS_MA0  84    // n=0 anti-spin msg vector, 8
#define WS_MS   92    // Ms[kp][k] = (ln2*g_w0) @ hs_w1, 8x8
#define WS_MA   156   // Ma[kp][k] = (ln2*g_w0) @ ha_w1, 8x8
#define WS_CS   220   // (X+g_b0)@hs_w1 + hs_b1, 8
#define WS_CA   228
#define WS_GO0  236   // ln2*g_w0 @ orb, 8
#define WS_GO1  244
#define WS_BASE 252   // (X+g_b0+g_b1)@orb, 1

__global__ void omni_setup(const float* __restrict__ X,   const float* __restrict__ w1,
                           const float* __restrict__ wb1, const float* __restrict__ w2,
                           const float* __restrict__ wb2, const float* __restrict__ hs_w,
                           const float* __restrict__ hs_b,const float* __restrict__ ha_w,
                           const float* __restrict__ ha_b,const float* __restrict__ g_w,
                           const float* __restrict__ g_b, const float* __restrict__ orb_w,
                           float* __restrict__ ws)
{
    const int t = threadIdx.x;
    const float L   = 1.4426950408889634f;   // log2(e)
    const float LN2 = 0.6931471805599453f;
    if (t < 48) {                                   // W1s, both n (w1 is (2,4,6) flat)
        ws[t] = w1[t] * L;
    } else if (t < 60) {                            // B1s
        ws[t] = wb1[t - 48] * L;
    } else if (t < 76) {                            // B2h
        const int u = t - 60, n = u >> 3, k = u & 7;
        float sw = 0.f;
        for (int a = 0; a < 6; ++a) sw += w2[n * 48 + a * KD + k];
        ws[t] = wb2[n * KD + k] * L - sw;
    } else if (t < 92) {                            // ms0 / ma0 (interaction 0 tables)
        const int u = t - 76, tab = u >> 3, k = u & 7;
        const float* mw = tab ? ha_w : hs_w;        // n=0 slice
        const float* mb = tab ? ha_b : hs_b;
        float acc = mb[k];
        for (int c = 0; c < ED; ++c) acc += X[c] * mw[c * KD + k];
        ws[t] = acc;
    } else if (t < 220) {                           // Ms / Ma (8x8)
        int u = t - 92; const int tab = u >> 6; u &= 63;
        const int kp = u >> 3, k = u & 7;
        const float* mw = (tab ? ha_w : hs_w) + ED * KD;   // n=1 slice
        float acc = 0.f;
        for (int c = 0; c < ED; ++c)
            acc += LN2 * g_w[kp * ED + c] * mw[c * KD + k]; // g_w n=0 slice
        ws[t] = acc;
    } else if (t < 236) {                           // Cs / Ca
        const int u = t - 220, tab = u >> 3, k = u & 7;
        const float* mw = (tab ? ha_w : hs_w) + ED * KD;
        const float* mb = (tab ? ha_b : hs_b) + KD;
        float acc = mb[k];
        for (int c = 0; c < ED; ++c) acc += (X[c] + g_b[c]) * mw[c * KD + k];
        ws[t] = acc;
    } else if (t < 252) {                           // go0 / go1
        const int u = t - 236, n = u >> 3, k = u & 7;
        float acc = 0.f;
        for (int c = 0; c < ED; ++c)
            acc += LN2 * g_w[n * KD * ED + k * ED + c] * orb_w[c];
        ws[t] = acc;
    } else if (t == 252) {                          // base
        float acc = 0.f;
        for (int c = 0; c < ED; ++c) acc += (X[c] + g_b[c] + g_b[ED + c]) * orb_w[c];
        ws[t] = acc;
    }
}

// log-domain w-subnet: racc[k] with true weight w[k] = ln2 * racc[k]
__device__ __forceinline__ void wnet(const float4 e,
                                     const float* __restrict__ vB1s,  // 6, VGPR uniform
                                     const float* __restrict__ vB2h,  // 8, VGPR uniform
                                     const float* __restrict__ sW1,   // 24, SGPR (log2e-folded)
                                     const float* __restrict__ sW2,   // (6,8), SGPR raw
                                     float* __restrict__ racc)
{
    float r[6];
    #pragma unroll
    for (int a = 0; a < 6; ++a) {
        float u = fmaf(e.x, sW1[a], vB1s[a]);
        u = fmaf(e.y, sW1[6 + a], u);
        u = fmaf(e.z, sW1[12 + a], u);
        u = fmaf(e.w, sW1[18 + a], u);
        r[a] = __builtin_amdgcn_logf(__builtin_amdgcn_exp2f(u) + 1.0f);  // log2(1+2^u)
    }
    #pragma unroll
    for (int k = 0; k < KD; ++k) {
        float acc = fmaf(r[0], sW2[k], vB2h[k]);
        #pragma unroll
        for (int a = 1; a < 6; ++a) acc = fmaf(r[a], sW2[a * KD + k], acc);
        racc[k] = acc;
    }
}

__global__ __launch_bounds__(128, 4) void omni_main(
    const float* __restrict__ dists_nuc,   // (B, NE, NA, DF)
    const float* __restrict__ dists_elec,  // (B, NE, NE, DF)
    const float* __restrict__ Y,           // (NA, KD)
    const float* __restrict__ w2,          // (2, 6, KD)
    const float* __restrict__ ws,          // precomputed constants
    float* __restrict__ out)               // (B,)
{
    const int tid  = threadIdx.x;
    const int h    = tid >> 6;          // wave: electrons of spin h
    const int lane = tid & 63;
    const int il   = lane & 15;
    const int jh   = lane >> 4;         // j quarter (j in [8jh, 8jh+8))
    const int ig   = 16 * h + il;       // this lane's electron
    const int b    = blockIdx.x;
    const int sj   = jh >> 1;           // spin of j range
    const bool same = (sj == h);
    const int t32  = same ? 0 : 32;

    __shared__ float msg[65][KD];       // n=1 table; row 64 = zeros
    __shared__ float part[2];
    if (tid < KD) msg[64][tid] = 0.0f;

    // ---- register-cache all distances (reused by both interactions) ----
    const float* de = dists_elec + (((size_t)b * NE + ig) * NE + 8 * jh) * DF;
    const float* dn = dists_nuc  + (((size_t)b * NE + ig) * NA + 2 * jh) * DF;
    float4 E[8];
    #pragma unroll
    for (int s = 0; s < 8; ++s) E[s] = ((const float4*)de)[s];
    const float4 F0 = ((const float4*)dn)[0];
    const float4 F1 = ((const float4*)dn)[1];
    const float4 Ya0 = ((const float4*)Y)[4 * jh + 0];
    const float4 Ya1 = ((const float4*)Y)[4 * jh + 1];
    const float4 Yb0 = ((const float4*)Y)[4 * jh + 2];
    const float4 Yb1 = ((const float4*)Y)[4 * jh + 3];

    // =================== interaction 0 (no LDS, no barrier) ===================
    float zr0[KD];
    {
        float vB1s[6], vB2h[KD], msel[KD];
        #pragma unroll
        for (int a = 0; a < 6; ++a) vB1s[a] = ws[WS_B1S0 + a];
        #pragma unroll
        for (int k = 0; k < KD; ++k) vB2h[k] = ws[WS_B2H0 + k];
        #pragma unroll
        for (int k = 0; k < KD; ++k) msel[k] = same ? ws[WS_MS0 + k] : ws[WS_MA0 + k];

        float zacc[KD];
        #pragma unroll
        for (int k = 0; k < KD; ++k) zacc[k] = 0.0f;
        const int scnt = ig - 8 * jh;   // self's s index if this group contains i
        #pragma unroll
        for (int s = 0; s < 8; ++s) {
            float racc[KD];
            wnet(E[s], vB1s, vB2h, ws + WS_W1S0, w2, racc);
            const float mf = (s == scnt) ? 0.0f : 1.0f;
            #pragma unroll
            for (int k = 0; k < KD; ++k) zacc[k] = fmaf(racc[k], mf, zacc[k]);
        }
        float z[KD];
        #pragma unroll
        for (int k = 0; k < KD; ++k) z[k] = zacc[k] * msel[k];
        {
            float racc[KD];
            wnet(F0, vB1s, vB2h, ws + WS_W1S0, w2, racc);
            z[0] = fmaf(racc[0], Ya0.x, z[0]); z[1] = fmaf(racc[1], Ya0.y, z[1]);
            z[2] = fmaf(racc[2], Ya0.z, z[2]); z[3] = fmaf(racc[3], Ya0.w, z[3]);
            z[4] = fmaf(racc[4], Ya1.x, z[4]); z[5] = fmaf(racc[5], Ya1.y, z[5]);
            z[6] = fmaf(racc[6], Ya1.z, z[6]); z[7] = fmaf(racc[7], Ya1.w, z[7]);
            wnet(F1, vB1s, vB2h, ws + WS_W1S0, w2, racc);
            z[0] = fmaf(racc[0], Yb0.x, z[0]); z[1] = fmaf(racc[1], Yb0.y, z[1]);
            z[2] = fmaf(racc[2], Yb0.z, z[2]); z[3] = fmaf(racc[3], Yb0.w, z[3]);
            z[4] = fmaf(racc[4], Yb1.x, z[4]); z[5] = fmaf(racc[5], Yb1.y, z[5]);
            z[6] = fmaf(racc[6], Yb1.z, z[6]); z[7] = fmaf(racc[7], Yb1.w, z[7]);
        }
        #pragma unroll
        for (int k = 0; k < KD; ++k) {
            z[k] += __shfl_xor(z[k], 16, 64);
            z[k] += __shfl_xor(z[k], 32, 64);
            zr0[k] = z[k];
        }
    }

    // =================== interaction 1 ===================
    // phase-1 via linearization: ms = Cs + zr0 @ Ms ; ma = Ca + zr0 @ Ma
    {
        float ms[KD], ma[KD];
        #pragma unroll
        for (int k = 0; k < KD; ++k) {
            float as = zr0[0] * ws[WS_MS + k];
            float aa = zr0[0] * ws[WS_MA + k];
            #pragma unroll
            for (int kp = 1; kp < KD; ++kp) {
                as = fmaf(zr0[kp], ws[WS_MS + kp * KD + k], as);
                aa = fmaf(zr0[kp], ws[WS_MA + kp * KD + k], aa);
            }
            ms[k] = as + ws[WS_CS + k];
            ma[k] = aa + ws[WS_CA + k];
        }
        if (jh == 0) {
            #pragma unroll
            for (int k = 0; k < KD; ++k) msg[ig][k] = ms[k];
        } else if (jh == 2) {
            #pragma unroll
            for (int k = 0; k < KD; ++k) msg[32 + ig][k] = ma[k];
        }
        __syncthreads();
    }

    float zr1[KD];
    {
        float vB1s[6], vB2h[KD];
        #pragma unroll
        for (int a = 0; a < 6; ++a) vB1s[a] = ws[WS_B1S1 + a];
        #pragma unroll
        for (int k = 0; k < KD; ++k) vB2h[k] = ws[WS_B2H1 + k];

        float z[KD];
        #pragma unroll
        for (int k = 0; k < KD; ++k) z[k] = 0.0f;
        #pragma unroll
        for (int s = 0; s < 8; ++s) {
            float racc[KD];
            wnet(E[s], vB1s, vB2h, ws + WS_W1S1, w2 + 48, racc);
            const int j = 8 * jh + s;
            const int row = (j == ig) ? 64 : (t32 + j);
            const float4 m0 = *(const float4*)&msg[row][0];
            const float4 m1 = *(const float4*)&msg[row][4];
            z[0] = fmaf(racc[0], m0.x, z[0]); z[1] = fmaf(racc[1], m0.y, z[1]);
            z[2] = fmaf(racc[2], m0.z, z[2]); z[3] = fmaf(racc[3], m0.w, z[3]);
            z[4] = fmaf(racc[4], m1.x, z[4]); z[5] = fmaf(racc[5], m1.y, z[5]);
            z[6] = fmaf(racc[6], m1.z, z[6]); z[7] = fmaf(racc[7], m1.w, z[7]);
        }
        {
            float racc[KD];
            wnet(F0, vB1s, vB2h, ws + WS_W1S1, w2 + 48, racc);
            z[0] = fmaf(racc[0], Ya0.x, z[0]); z[1] = fmaf(racc[1], Ya0.y, z[1]);
            z[2] = fmaf(racc[2], Ya0.z, z[2]); z[3] = fmaf(racc[3], Ya0.w, z[3]);
            z[4] = fmaf(racc[4], Ya1.x, z[4]); z[5] = fmaf(racc[5], Ya1.y, z[5]);
            z[6] = fmaf(racc[6], Ya1.z, z[6]); z[7] = fmaf(racc[7], Ya1.w, z[7]);
            wnet(F1, vB1s, vB2h, ws + WS_W1S1, w2 + 48, racc);
            z[0] = fmaf(racc[0], Yb0.x, z[0]); z[1] = fmaf(racc[1], Yb0.y, z[1]);
            z[2] = fmaf(racc[2], Yb0.z, z[2]); z[3] = fmaf(racc[3], Yb0.w, z[3]);
            z[4] = fmaf(racc[4], Yb1.x, z[4]); z[5] = fmaf(racc[5], Yb1.y, z[5]);
            z[6] = fmaf(racc[6], Yb1.z, z[6]); z[7] = fmaf(racc[7], Yb1.w, z[7]);
        }
        #pragma unroll
        for (int k = 0; k < KD; ++k) {
            z[k] += __shfl_xor(z[k], 16, 64);
            z[k] += __shfl_xor(z[k], 32, 64);
            zr1[k] = z[k];
        }
    }

    // =================== epilogue: dot = base + zr0@go0 + zr1@go1 ===================
    float dot = 0.0f;
    #pragma unroll
    for (int k = 0; k < KD; ++k) dot = fmaf(zr0[k], ws[WS_GO0 + k], dot);
    #pragma unroll
    for (int k = 0; k < KD; ++k) dot = fmaf(zr1[k], ws[WS_GO1 + k], dot);
    dot += ws[WS_BASE];
    dot *= 0.25f;    // each electron replicated across 4 lanes
    #pragma unroll
    for (int off = 1; off < 64; off <<= 1) dot += __shfl_xor(dot, off, 64);
    if (lane == 0) part[h] = dot;
    __syncthreads();
    if (tid == 0) out[b] = part[0] + part[1];
}

extern "C" void kernel_launch(void* const* d_in, const int* in_sizes, int n_in,
                              void* d_out, int out_size, void* d_ws, size_t ws_size,
                              hipStream_t stream) {
    const float* dists_nuc  = (const float*)d_in[0];
    const float* dists_elec = (const float*)d_in[1];
    const float* X     = (const float*)d_in[2];
    const float* Y     = (const float*)d_in[3];
    const float* w1    = (const float*)d_in[4];
    const float* wb1   = (const float*)d_in[5];
    const float* w2    = (const float*)d_in[6];
    const float* wb2   = (const float*)d_in[7];
    const float* hs_w  = (const float*)d_in[8];
    const float* hs_b  = (const float*)d_in[9];
    const float* ha_w  = (const float*)d_in[10];
    const float* ha_b  = (const float*)d_in[11];
    const float* g_w   = (const float*)d_in[12];
    const float* g_b   = (const float*)d_in[13];
    const float* orb_w = (const float*)d_in[14];
    float* out = (float*)d_out;
    float* ws  = (float*)d_ws;

    omni_setup<<<1, 256, 0, stream>>>(X, w1, wb1, w2, wb2, hs_w, hs_b,
                                      ha_w, ha_b, g_w, g_b, orb_w, ws);
    omni_main<<<BATCH, 128, 0, stream>>>(dists_nuc, dists_elec, Y, w2, ws, out);
}